// Round 4
// baseline (2508.676 us; speedup 1.0000x reference)
//
#include <hip/hip_runtime.h>

// GCN 2-layer, scatter-atomic with aggregate-before-transform.
// L1: g1 = dinv⊙x (5 feats); acc1[d] = g1[d] + Σ_{s->d} g1[s]  (25M f32 atomics)
//     h = relu(dinv*(acc1@W1)+b1); y2 = dinv*(h@W2)
// L2: acc2[d] = y2[d] + Σ_{s->d} y2[s]  (20M f32 atomics)
//     out = relu(dinv*acc2 + b2)

constexpr int F0 = 5, F1 = 16, F2 = 4;

__global__ void zero_counts(int* __restrict__ cnt, int n) {
    int i = blockIdx.x * blockDim.x + threadIdx.x;
    if (i < n) cnt[i] = 0;
}

__global__ void count_deg(const int* __restrict__ dst, int* __restrict__ cnt, int ne) {
    int e = blockIdx.x * blockDim.x + threadIdx.x;
    if (e < ne) atomicAdd(&cnt[dst[e]], 1);  // fire-and-forget int atomic
}

__global__ void compute_dinv(const int* __restrict__ cnt, float* __restrict__ dinv, int n) {
    int i = blockIdx.x * blockDim.x + threadIdx.x;
    if (i < n) dinv[i] = rsqrtf((float)(cnt[i] + 1));
}

// g1[i] = dinv[i]*x[i] (rows padded to 8 floats); acc1 seeded = g1 (self loop)
__global__ void make_g1(const float* __restrict__ x, const float* __restrict__ dinv,
                        float* __restrict__ g1, float* __restrict__ acc1, int n) {
    int i = blockIdx.x * blockDim.x + threadIdx.x;
    if (i >= n) return;
    float di = dinv[i];
    float v[F0];
#pragma unroll
    for (int j = 0; j < F0; j++) v[j] = di * x[(size_t)i * F0 + j];
    float4 lo = make_float4(v[0], v[1], v[2], v[3]);
    *reinterpret_cast<float4*>(g1 + (size_t)i * 8) = lo;
    g1[(size_t)i * 8 + 4] = v[4];
    *reinterpret_cast<float4*>(acc1 + (size_t)i * 8) = lo;
    acc1[(size_t)i * 8 + 4] = v[4];
}

// one thread per edge: 5 fire-and-forget atomics
__global__ void scatter_g1(const int* __restrict__ src, const int* __restrict__ dst,
                           const float* __restrict__ g1, float* __restrict__ acc1, int ne) {
    int e = blockIdx.x * blockDim.x + threadIdx.x;
    if (e >= ne) return;
    int s = src[e], d = dst[e];
    const float* gs = g1 + (size_t)s * 8;
    float4 v = *reinterpret_cast<const float4*>(gs);
    float v4 = gs[4];
    float* ad = acc1 + (size_t)d * 8;
    atomicAdd(ad + 0, v.x);
    atomicAdd(ad + 1, v.y);
    atomicAdd(ad + 2, v.z);
    atomicAdd(ad + 3, v.w);
    atomicAdd(ad + 4, v4);
}

// h = relu(dinv*(acc1@W1)+b1); y2 = dinv*(h@W2); acc2 seeded = y2
__global__ void l12_fused(const float* __restrict__ acc1, const float* __restrict__ dinv,
                          const float* __restrict__ W1, const float* __restrict__ b1,
                          const float* __restrict__ W2, float* __restrict__ y2,
                          float* __restrict__ acc2, int n) {
    __shared__ float w1[F0 * F1], bb1[F1], w2[F1 * F2];
    int t = threadIdx.x;
    if (t < F0 * F1) w1[t] = W1[t];
    if (t < F1) bb1[t] = b1[t];
    if (t < F1 * F2) w2[t] = W2[t];
    __syncthreads();
    int i = blockIdx.x * blockDim.x + t;
    if (i >= n) return;
    const float* ai = acc1 + (size_t)i * 8;
    float4 alo = *reinterpret_cast<const float4*>(ai);
    float a4 = ai[4];
    float di = dinv[i];
    float h[F1];
#pragma unroll
    for (int j = 0; j < F1; j++) {
        float v = alo.x * w1[0 * F1 + j] + alo.y * w1[1 * F1 + j] + alo.z * w1[2 * F1 + j] +
                  alo.w * w1[3 * F1 + j] + a4 * w1[4 * F1 + j];
        v = di * v + bb1[j];
        h[j] = v > 0.f ? v : 0.f;
    }
    float4 o;
    float* op = &o.x;
#pragma unroll
    for (int j = 0; j < F2; j++) {
        float v = 0.f;
#pragma unroll
        for (int k = 0; k < F1; k++) v += h[k] * w2[k * F2 + j];
        op[j] = di * v;
    }
    *reinterpret_cast<float4*>(y2 + (size_t)i * 4) = o;
    *reinterpret_cast<float4*>(acc2 + (size_t)i * 4) = o;
}

// one thread per edge: 4 fire-and-forget atomics
__global__ void scatter_y2(const int* __restrict__ src, const int* __restrict__ dst,
                           const float* __restrict__ y2, float* __restrict__ acc2, int ne) {
    int e = blockIdx.x * blockDim.x + threadIdx.x;
    if (e >= ne) return;
    int s = src[e], d = dst[e];
    float4 v = *reinterpret_cast<const float4*>(y2 + (size_t)s * 4);
    float* ad = acc2 + (size_t)d * 4;
    atomicAdd(ad + 0, v.x);
    atomicAdd(ad + 1, v.y);
    atomicAdd(ad + 2, v.z);
    atomicAdd(ad + 3, v.w);
}

__global__ void finish(const float* __restrict__ acc2, const float* __restrict__ b2,
                       const float* __restrict__ dinv, float* __restrict__ out, int n) {
    int i = blockIdx.x * blockDim.x + threadIdx.x;
    if (i >= n) return;
    float di = dinv[i];
    float4 a = reinterpret_cast<const float4*>(acc2)[i];
    float4 r;
    r.x = fmaxf(di * a.x + b2[0], 0.f);
    r.y = fmaxf(di * a.y + b2[1], 0.f);
    r.z = fmaxf(di * a.z + b2[2], 0.f);
    r.w = fmaxf(di * a.w + b2[3], 0.f);
    reinterpret_cast<float4*>(out)[i] = r;
}

extern "C" void kernel_launch(void* const* d_in, const int* in_sizes, int n_in,
                              void* d_out, int out_size, void* d_ws, size_t ws_size,
                              hipStream_t stream) {
    const float* x  = (const float*)d_in[0];
    const int*   ei = (const int*)d_in[1];   // [2, E]
    const float* W1 = (const float*)d_in[2];
    const float* b1 = (const float*)d_in[3];
    const float* W2 = (const float*)d_in[4];
    const float* b2 = (const float*)d_in[5];
    float* out = (float*)d_out;

    const int n  = in_sizes[0] / F0;   // 250000
    const int ne = in_sizes[1] / 2;    // 5000000
    const int* src = ei;
    const int* dst = ei + ne;

    // workspace, 256B-aligned; total ~26 MB
    char* ws = (char*)d_ws;
    size_t off = 0;
    auto alloc = [&](size_t bytes) { void* p = ws + off; off += (bytes + 255) & ~255ull; return p; };
    int*   cnt  = (int*)alloc((size_t)n * 4);
    float* dinv = (float*)alloc((size_t)n * 4);
    float* g1   = (float*)alloc((size_t)n * 8 * 4);   // 8 MB
    float* acc1 = (float*)alloc((size_t)n * 8 * 4);   // 8 MB
    float* y2   = (float*)alloc((size_t)n * 4 * 4);   // 4 MB
    float* acc2 = (float*)alloc((size_t)n * 4 * 4);   // 4 MB

    const int B = 256;
    zero_counts<<<(n + B - 1) / B, B, 0, stream>>>(cnt, n);
    count_deg<<<(ne + B - 1) / B, B, 0, stream>>>(dst, cnt, ne);
    compute_dinv<<<(n + B - 1) / B, B, 0, stream>>>(cnt, dinv, n);

    make_g1<<<(n + B - 1) / B, B, 0, stream>>>(x, dinv, g1, acc1, n);
    scatter_g1<<<(ne + B - 1) / B, B, 0, stream>>>(src, dst, g1, acc1, ne);
    l12_fused<<<(n + B - 1) / B, B, 0, stream>>>(acc1, dinv, W1, b1, W2, y2, acc2, n);
    scatter_y2<<<(ne + B - 1) / B, B, 0, stream>>>(src, dst, y2, acc2, ne);
    finish<<<(n + B - 1) / B, B, 0, stream>>>(acc2, b2, dinv, out, n);
}

// Round 5
// 420.094 us; speedup vs baseline: 5.9717x; 5.9717x over previous
//
#include <hip/hip_runtime.h>

// GCN 2-layer via bucket-binned LDS aggregation (no global float atomics).
// Nodes partitioned into buckets of 1024; edges binned by dst bucket once,
// then 3 bucket passes (deg, agg-layer1 on dinv*x [5ch], agg-layer2 on y2 [4ch])
// accumulate in LDS and write out coalesced.

constexpr int F0 = 5, F1 = 16, F2 = 4;
constexpr int BB = 10;                    // bucket bits -> 1024 nodes/bucket
constexpr int BN = 1 << BB;
constexpr int SBITS = 18;                 // src fits in 18 bits (n=250000 < 262144)
constexpr unsigned SMASK = (1u << SBITS) - 1;
constexpr int P1_T = 256, P1_EPT = 16, P1_CHUNK = P1_T * P1_EPT;

__global__ void zero_ints(int* __restrict__ p, int n) {
    int i = blockIdx.x * blockDim.x + threadIdx.x;
    if (i < n) p[i] = 0;
}

// per-WG LDS histogram of dst>>BB, merged into global bcnt[256]
__global__ void bucket_count(const int* __restrict__ dst, int ne, int* __restrict__ bcnt) {
    __shared__ int h[256];
    int t = threadIdx.x;
    h[t] = 0;
    __syncthreads();
    for (int e = blockIdx.x * blockDim.x + t; e < ne; e += gridDim.x * blockDim.x)
        atomicAdd(&h[dst[e] >> BB], 1);
    __syncthreads();
    if (h[t]) atomicAdd(&bcnt[t], h[t]);
}

// exclusive scan of 256 bucket counts -> bstart[257], wpos[256]
__global__ void scan_buckets(const int* __restrict__ bcnt, int* __restrict__ bstart,
                             int* __restrict__ wpos, int ne) {
    __shared__ int s[256];
    int t = threadIdx.x;
    s[t] = bcnt[t];
    __syncthreads();
    for (int o = 1; o < 256; o <<= 1) {
        int v = (t >= o) ? s[t - o] : 0;
        __syncthreads();
        s[t] += v;
        __syncthreads();
    }
    int excl = s[t] - bcnt[t];
    bstart[t] = excl;
    wpos[t] = excl;
    if (t == 255) bstart[256] = ne;
}

// bin edges by dst bucket: packed entry = (dst&1023)<<18 | src
__global__ void bin_edges(const int* __restrict__ src, const int* __restrict__ dst, int ne,
                          int* __restrict__ wpos, unsigned* __restrict__ binned) {
    __shared__ int hist[256];
    __shared__ int base[256];
    int t = threadIdx.x;
    hist[t] = 0;
    __syncthreads();
    int start = blockIdx.x * P1_CHUNK;
    int sv[P1_EPT], dv[P1_EPT];
#pragma unroll
    for (int k = 0; k < P1_EPT; k++) {
        int e = start + k * P1_T + t;
        if (e < ne) {
            sv[k] = src[e]; dv[k] = dst[e];
            atomicAdd(&hist[dv[k] >> BB], 1);
        } else sv[k] = -1;
    }
    __syncthreads();
    int h = hist[t];
    if (h) base[t] = atomicAdd(&wpos[t], h);
    __syncthreads();
    hist[t] = 0;
    __syncthreads();
#pragma unroll
    for (int k = 0; k < P1_EPT; k++) {
        if (sv[k] >= 0) {
            int b = dv[k] >> BB;
            int r = atomicAdd(&hist[b], 1);
            binned[base[b] + r] = ((unsigned)(dv[k] & (BN - 1)) << SBITS) | (unsigned)sv[k];
        }
    }
}

// per-bucket degree count in LDS -> dinv
__global__ void __launch_bounds__(1024)
bucket_deg(const unsigned* __restrict__ binned, const int* __restrict__ bstart,
           float* __restrict__ dinv, int n) {
    __shared__ int cnt[BN];
    int b = blockIdx.x, nbase = b << BB;
    for (int i = threadIdx.x; i < BN; i += blockDim.x) cnt[i] = 0;
    __syncthreads();
    int e0 = bstart[b], e1 = bstart[b + 1];
    for (int e = e0 + threadIdx.x; e < e1; e += blockDim.x)
        atomicAdd(&cnt[binned[e] >> SBITS], 1);
    __syncthreads();
    for (int i = threadIdx.x; i < BN; i += blockDim.x) {
        int node = nbase + i;
        if (node < n) dinv[node] = rsqrtf((float)(cnt[i] + 1));
    }
}

// g1[i] = dinv[i]*x[i], rows padded to 8 floats (pads unwritten/unread)
__global__ void make_g1(const float* __restrict__ x, const float* __restrict__ dinv,
                        float* __restrict__ g1, int n) {
    int i = blockIdx.x * blockDim.x + threadIdx.x;
    if (i >= n) return;
    float di = dinv[i];
    const float* xi = x + (size_t)i * F0;
    float4 lo = make_float4(di * xi[0], di * xi[1], di * xi[2], di * xi[3]);
    *reinterpret_cast<float4*>(g1 + (size_t)i * 8) = lo;
    g1[(size_t)i * 8 + 4] = di * xi[4];
}

// per-bucket layer-1 aggregation: acc[d] += g1[s] (LDS float atomics)
__global__ void __launch_bounds__(1024)
bucket_agg1(const unsigned* __restrict__ binned, const int* __restrict__ bstart,
            const float* __restrict__ g1, float* __restrict__ acc1, int n) {
    __shared__ float acc[BN * 5];  // 20 KB
    int b = blockIdx.x, nbase = b << BB;
    for (int i = threadIdx.x; i < BN * 5; i += blockDim.x) acc[i] = 0.f;
    __syncthreads();
    int e0 = bstart[b], e1 = bstart[b + 1];
    for (int e = e0 + threadIdx.x; e < e1; e += blockDim.x) {
        unsigned u = binned[e];
        int ld = u >> SBITS;
        int s = u & SMASK;
        const float* gs = g1 + (size_t)s * 8;
        float4 lo = *reinterpret_cast<const float4*>(gs);
        float v4 = gs[4];
        float* a = acc + ld * 5;
        atomicAdd(a + 0, lo.x);
        atomicAdd(a + 1, lo.y);
        atomicAdd(a + 2, lo.z);
        atomicAdd(a + 3, lo.w);
        atomicAdd(a + 4, v4);
    }
    __syncthreads();
    for (int i = threadIdx.x; i < BN; i += blockDim.x) {
        int node = nbase + i;
        if (node < n) {
            float* a = acc + i * 5;
            float4 lo = make_float4(a[0], a[1], a[2], a[3]);
            *reinterpret_cast<float4*>(acc1 + (size_t)node * 8) = lo;
            acc1[(size_t)node * 8 + 4] = a[4];
        }
    }
}

// total = acc1+g1 (self loop); h=relu(dinv*(total@W1)+b1); y2=dinv*(h@W2)
__global__ void l12_fused(const float* __restrict__ acc1, const float* __restrict__ g1,
                          const float* __restrict__ dinv,
                          const float* __restrict__ W1, const float* __restrict__ b1,
                          const float* __restrict__ W2, float* __restrict__ y2, int n) {
    __shared__ float w1[F0 * F1], bb1[F1], w2[F1 * F2];
    int t = threadIdx.x;
    if (t < F0 * F1) w1[t] = W1[t];
    if (t < F1) bb1[t] = b1[t];
    if (t < F1 * F2) w2[t] = W2[t];
    __syncthreads();
    int i = blockIdx.x * blockDim.x + t;
    if (i >= n) return;
    const float* ar = acc1 + (size_t)i * 8;
    const float* gr = g1 + (size_t)i * 8;
    float4 al = *reinterpret_cast<const float4*>(ar);
    float4 gl = *reinterpret_cast<const float4*>(gr);
    float a0 = al.x + gl.x, a1 = al.y + gl.y, a2 = al.z + gl.z, a3 = al.w + gl.w;
    float a4 = ar[4] + gr[4];
    float di = dinv[i];
    float h[F1];
#pragma unroll
    for (int j = 0; j < F1; j++) {
        float v = a0 * w1[0 * F1 + j] + a1 * w1[1 * F1 + j] + a2 * w1[2 * F1 + j] +
                  a3 * w1[3 * F1 + j] + a4 * w1[4 * F1 + j];
        v = di * v + bb1[j];
        h[j] = v > 0.f ? v : 0.f;
    }
    float4 o;
    float* op = &o.x;
#pragma unroll
    for (int j = 0; j < F2; j++) {
        float v = 0.f;
#pragma unroll
        for (int k = 0; k < F1; k++) v += h[k] * w2[k * F2 + j];
        op[j] = di * v;
    }
    *reinterpret_cast<float4*>(y2 + (size_t)i * 4) = o;
}

// per-bucket layer-2 aggregation + fused finish: out = relu(dinv*(acc+y2_self)+b2)
__global__ void __launch_bounds__(1024)
bucket_agg2(const unsigned* __restrict__ binned, const int* __restrict__ bstart,
            const float* __restrict__ y2, const float* __restrict__ dinv,
            const float* __restrict__ b2, float* __restrict__ out, int n) {
    __shared__ float acc[BN * 4];  // 16 KB
    int b = blockIdx.x, nbase = b << BB;
    for (int i = threadIdx.x; i < BN * 4; i += blockDim.x) acc[i] = 0.f;
    __syncthreads();
    int e0 = bstart[b], e1 = bstart[b + 1];
    for (int e = e0 + threadIdx.x; e < e1; e += blockDim.x) {
        unsigned u = binned[e];
        int ld = u >> SBITS;
        int s = u & SMASK;
        float4 v = *reinterpret_cast<const float4*>(y2 + (size_t)s * 4);
        float* a = acc + ld * 4;
        atomicAdd(a + 0, v.x);
        atomicAdd(a + 1, v.y);
        atomicAdd(a + 2, v.z);
        atomicAdd(a + 3, v.w);
    }
    __syncthreads();
    float c0 = b2[0], c1 = b2[1], c2 = b2[2], c3 = b2[3];
    for (int i = threadIdx.x; i < BN; i += blockDim.x) {
        int node = nbase + i;
        if (node < n) {
            float4 self = *reinterpret_cast<const float4*>(y2 + (size_t)node * 4);
            float di = dinv[node];
            float* a = acc + i * 4;
            float4 r;
            r.x = fmaxf(di * (a[0] + self.x) + c0, 0.f);
            r.y = fmaxf(di * (a[1] + self.y) + c1, 0.f);
            r.z = fmaxf(di * (a[2] + self.z) + c2, 0.f);
            r.w = fmaxf(di * (a[3] + self.w) + c3, 0.f);
            *reinterpret_cast<float4*>(out + (size_t)node * 4) = r;
        }
    }
}

extern "C" void kernel_launch(void* const* d_in, const int* in_sizes, int n_in,
                              void* d_out, int out_size, void* d_ws, size_t ws_size,
                              hipStream_t stream) {
    const float* x  = (const float*)d_in[0];
    const int*   ei = (const int*)d_in[1];   // [2, E]
    const float* W1 = (const float*)d_in[2];
    const float* b1 = (const float*)d_in[3];
    const float* W2 = (const float*)d_in[4];
    const float* b2 = (const float*)d_in[5];
    float* out = (float*)d_out;

    const int n  = in_sizes[0] / F0;   // 250000
    const int ne = in_sizes[1] / 2;    // 5000000
    const int* src = ei;
    const int* dst = ei + ne;
    const int NB = (n + BN - 1) >> BB; // 245 buckets

    // workspace, 256B-aligned; total ~41 MB
    char* ws = (char*)d_ws;
    size_t off = 0;
    auto alloc = [&](size_t bytes) { void* p = ws + off; off += (bytes + 255) & ~255ull; return p; };
    int*      bcnt   = (int*)alloc(256 * 4);
    int*      bstart = (int*)alloc(257 * 4);
    int*      wpos   = (int*)alloc(256 * 4);
    float*    dinv   = (float*)alloc((size_t)n * 4);        // 1 MB
    unsigned* binned = (unsigned*)alloc((size_t)ne * 4);    // 20 MB
    float*    g1     = (float*)alloc((size_t)n * 8 * 4);    // 8 MB
    float*    acc1   = (float*)alloc((size_t)n * 8 * 4);    // 8 MB
    float*    y2     = (float*)alloc((size_t)n * 4 * 4);    // 4 MB

    zero_ints<<<1, 256, 0, stream>>>(bcnt, 256);
    bucket_count<<<1024, 256, 0, stream>>>(dst, ne, bcnt);
    scan_buckets<<<1, 256, 0, stream>>>(bcnt, bstart, wpos, ne);
    bin_edges<<<(ne + P1_CHUNK - 1) / P1_CHUNK, P1_T, 0, stream>>>(src, dst, ne, wpos, binned);

    bucket_deg<<<NB, 1024, 0, stream>>>(binned, bstart, dinv, n);
    make_g1<<<(n + 255) / 256, 256, 0, stream>>>(x, dinv, g1, n);
    bucket_agg1<<<NB, 1024, 0, stream>>>(binned, bstart, g1, acc1, n);
    l12_fused<<<(n + 255) / 256, 256, 0, stream>>>(acc1, g1, dinv, W1, b1, W2, y2, n);
    bucket_agg2<<<NB, 1024, 0, stream>>>(binned, bstart, y2, dinv, b2, out, n);
}